// Round 3
// baseline (348.557 us; speedup 1.0000x reference)
//
#include <hip/hip_runtime.h>
#include <hip/hip_bf16.h>

typedef __attribute__((ext_vector_type(8))) short bf16x8;  // 8 bf16 = 4 VGPRs
typedef __attribute__((ext_vector_type(4))) float f32x4;   // MFMA C/D

#define BIGC 10000.0f
#define TPW 8          // tiles (of 16 points) per wave per launch
#define WAVES 4        // waves per block
#define HSTRIDE 144    // LDS h-row stride in bytes (16B-aligned, breaks pow2 banks)

__device__ __forceinline__ float fast_exp2(float x) { return __builtin_amdgcn_exp2f(x); }
__device__ __forceinline__ float fast_log2(float x) { return __builtin_amdgcn_logf(x); }
__device__ __forceinline__ float fast_rcp(float x)  { return __builtin_amdgcn_rcpf(x); }

__device__ __forceinline__ float fast_tanh(float x) {
    const float ax = fabsf(x);
    const float e  = fast_exp2(ax * 2.8853900817779268f);   // e^(2|x|)
    const float r  = 1.0f - 2.0f * fast_rcp(e + 1.0f);
    return copysignf(r, x);
}
__device__ __forceinline__ float fast_softplus(float v) {
    const float e = fast_exp2(fabsf(v) * -1.4426950408889634f);  // exp(-|v|)
    const float l = fast_log2(1.0f + e) * 0.6931471805599453f;   // ln(1+e)
    return fmaxf(v, 0.0f) + l;
}
__device__ __forceinline__ short f2bf(float f) {
    __hip_bfloat16 h = __float2bfloat16(f);   // RNE
    return __builtin_bit_cast(short, h);
}

// MFMA 16x16x32 layouts (guide-verified, m89/m91):
//   A: lane holds A[m = lane&15][k = (lane>>4)*8 + j], j=0..7
//   B: lane holds B[k = (lane>>4)*8 + j][n = lane&15]
//   C/D: lane holds D[row = (lane>>4)*4 + reg][col = lane&15]
__global__ void __launch_bounds__(256) coupling_mfma(
    const float* __restrict__ x, const float* __restrict__ t_feat,
    const float* __restrict__ mask, const float* __restrict__ W1,
    const float* __restrict__ b1, const float* __restrict__ W2,
    const float* __restrict__ b2, float* __restrict__ out, int n)
{
    __shared__ __align__(16) char lds_h[WAVES * 16 * HSTRIDE]; // h tiles, bf16
    __shared__ float lds_d[WAVES][16][12];                     // d per point

    const int wave = threadIdx.x >> 6;
    const int lane = threadIdx.x & 63;
    const int m    = lane & 15;
    const int q    = lane >> 4;

    // ---- weight fragments: loaded ONCE per wave, resident in VGPRs ----
    bf16x8 w1f[4];   // GEMM1 B-frags: hid tile a -> B[k][16a+m], k=q*8+j (pad k>=18 with 0)
#pragma unroll
    for (int a = 0; a < 4; ++a) {
        bf16x8 f;
#pragma unroll
        for (int j = 0; j < 8; ++j) {
            const int k = q * 8 + j;
            const float v = (k < 18) ? W1[k * 64 + 16 * a + m] : 0.0f;
            f[j] = f2bf(v);
        }
        w1f[a] = f;
    }
    bf16x8 w2f[2];   // GEMM2 B-frags: B[k = 32*fi + q*8+j][m] (pad n>=10 with 0)
#pragma unroll
    for (int fi = 0; fi < 2; ++fi) {
        bf16x8 f;
#pragma unroll
        for (int j = 0; j < 8; ++j) {
            const int k = 32 * fi + q * 8 + j;
            const float v = (m < 10) ? W2[k * 10 + m] : 0.0f;
            f[j] = f2bf(v);
        }
        w2f[fi] = f;
    }
    float bias1[4];
#pragma unroll
    for (int a = 0; a < 4; ++a) bias1[a] = b1[16 * a + m];
    const float bias2 = (m < 10) ? b2[m] : 0.0f;
    const float m0 = mask[0], m1 = mask[1];

    char* const hbase = &lds_h[wave * 16 * HSTRIDE];
    const int total_tiles = n >> 4;

    const int tile0 = blockIdx.x * (WAVES * TPW);
    for (int it = 0; it < TPW; ++it) {
        const int tile = tile0 + it * WAVES + wave;
        const int p0   = tile * 16;

        // ---- assemble A-fragment of z = [tanh(x0),tanh(x1),t_feat(16), 0-pad] ----
        // row (point) = p0+m, k = q*8+j.  k in [2,18) -> t_feat[k-2]; k<2 -> tanh.
        const long prow = min((long)(p0 + m), (long)n - 1);
        const float* trow = t_feat + prow * 16;
        bf16x8 af;
#pragma unroll
        for (int j = 0; j < 8; ++j) {
            const int k = q * 8 + j;
            float v = 0.0f;
            if (k >= 2 && k < 18) v = trow[k - 2];
            af[j] = f2bf(v);
        }
        if (q == 0) {
            const float* xr = x + prow * 3;
            af[0] = f2bf(fast_tanh(xr[0]));
            af[1] = f2bf(fast_tanh(xr[1]));
        }

        // ---- GEMM1: h(16x64) = z @ W1 + b1, 4 MFMAs over hid tiles ----
        f32x4 acc[4];
#pragma unroll
        for (int a = 0; a < 4; ++a) {
            f32x4 c; c[0] = c[1] = c[2] = c[3] = bias1[a];
            acc[a] = __builtin_amdgcn_mfma_f32_16x16x32_bf16(af, w1f[a], c, 0, 0, 0);
        }

        // ---- relu + C-layout -> LDS h[point][hid] (bf16, row stride 144B) ----
#pragma unroll
        for (int a = 0; a < 4; ++a) {
#pragma unroll
            for (int r = 0; r < 4; ++r) {
                const float hv = fmaxf(acc[a][r], 0.0f);
                const int point = q * 4 + r;
                const int hid   = 16 * a + m;
                *(short*)(hbase + point * HSTRIDE + hid * 2) = f2bf(hv);
            }
        }
        __syncthreads();

        // ---- GEMM2: d(16x10) = h @ W2 + b2, K=64 as 2 MFMAs ----
        // A-frag read: h[m][q*8+j (+32)] -> 16B-aligned ds_read_b128
        const bf16x8 a2_0 = *(const bf16x8*)(hbase + m * HSTRIDE + q * 16);
        const bf16x8 a2_1 = *(const bf16x8*)(hbase + m * HSTRIDE + 64 + q * 16);
        f32x4 cd; cd[0] = cd[1] = cd[2] = cd[3] = bias2;
        cd = __builtin_amdgcn_mfma_f32_16x16x32_bf16(a2_0, w2f[0], cd, 0, 0, 0);
        cd = __builtin_amdgcn_mfma_f32_16x16x32_bf16(a2_1, w2f[1], cd, 0, 0, 0);

        // ---- softplus + write d[point][feat] to LDS ----
#pragma unroll
        for (int r = 0; r < 4; ++r) {
            const float dv = fast_softplus(cd[r]) + 0.0001f;
            if (m < 10) lds_d[wave][q * 4 + r][m] = dv;
        }
        __syncthreads();

        // ---- interp + store: lanes 0..15, one point each ----
        if (q == 0) {
            const int p = p0 + m;
            if (p < n) {
                const float* dd = lds_d[wave][m];
                const float dxl2 = dd[0], dxl1 = dd[1], dxr1 = dd[2], dxr2 = dd[3];
                const float dyl2 = dd[4], dyl1 = dd[5], dyr1 = dd[6], dyr2 = dd[7];
                const float kl = dd[8] * 2.0f, kr = dd[9] * 2.0f;

                const float xL1 = -dxl1,        yL1 = -dyl1;
                const float xL2 = -dxl1 - dxl2, yL2 = -dyl1 - dyl2;
                const float xR1 = dxr1,         yR1 = dyr1;
                const float xR2 = dxr1 + dxr2,  yR2 = dyr1 + dyr2;
                const float xR3 = xR2 + BIGC,   yR3 = fmaf(kr, BIGC, yR2);
                const float xL3 = xL2 - BIGC,   yL3 = fmaf(-kl, BIGC, yL2);

                const float* xr = x + (long)p * 3;
                const float x0v = xr[0], x1v = xr[1], x2v = xr[2];

                float qx = fminf(fmaxf(x2v, xL3 * 0.99f), xR3 * 0.99f);
                float xl = xL3, xrr = xL2, yl = yL3, yr = yL2;
                if (qx >= xL2) { xl = xL2; xrr = xL1; yl = yL2; yr = yL1; }
                if (qx >= xL1) { xl = xL1; xrr = xR1; yl = yL1; yr = yR1; }
                if (qx >= xR1) { xl = xR1; xrr = xR2; yl = yR1; yr = yR2; }
                if (qx >= xR2) { xl = xR2; xrr = xR3; yl = yR2; yr = yR3; }
                const float slope = (yr - yl) * fast_rcp(xrr - xl);
                const float res = fmaf(slope, qx - xl, yl);

                out[(long)p * 3 + 0] = x0v * m0;
                out[(long)p * 3 + 1] = x1v * m1;
                out[(long)p * 3 + 2] = res;
            }
        }
    }
}

extern "C" void kernel_launch(void* const* d_in, const int* in_sizes, int n_in,
                              void* d_out, int out_size, void* d_ws, size_t ws_size,
                              hipStream_t stream) {
    const float* x      = (const float*)d_in[0];
    const float* t_feat = (const float*)d_in[1];
    const float* mask   = (const float*)d_in[2];
    const float* W1     = (const float*)d_in[3];
    const float* b1     = (const float*)d_in[4];
    const float* W2     = (const float*)d_in[5];
    const float* b2     = (const float*)d_in[6];
    float* out = (float*)d_out;

    const int n = in_sizes[0] / 3;               // 2097152 points
    const int tiles = (n + 15) / 16;             // 131072
    const int tiles_per_block = WAVES * TPW;     // 32
    const int grid = (tiles + tiles_per_block - 1) / tiles_per_block;  // 4096
    coupling_mfma<<<grid, 256, 0, stream>>>(x, t_feat, mask, W1, b1, W2, b2, out, n);
}

// Round 4
// 266.533 us; speedup vs baseline: 1.3077x; 1.3077x over previous
//
#include <hip/hip_runtime.h>
#include <hip/hip_bf16.h>

typedef __attribute__((ext_vector_type(8))) short bf16x8;  // 8 bf16 = 4 VGPRs
typedef __attribute__((ext_vector_type(4))) float f32x4;   // MFMA C/D

#define BIGC 10000.0f
#define TPW 4          // macro-iterations (64 points each) per wave
#define WAVES 4
#define HSTRIDE 144    // h row stride in bytes (16B-aligned, odd multiple of 16)

__device__ __forceinline__ float fast_exp2(float x) { return __builtin_amdgcn_exp2f(x); }
__device__ __forceinline__ float fast_log2(float x) { return __builtin_amdgcn_logf(x); }
__device__ __forceinline__ float fast_rcp(float x)  { return __builtin_amdgcn_rcpf(x); }

__device__ __forceinline__ float fast_tanh(float x) {
    const float ax = fabsf(x);
    const float e  = fast_exp2(ax * 2.8853900817779268f);   // e^(2|x|)
    const float r  = 1.0f - 2.0f * fast_rcp(e + 1.0f);
    return copysignf(r, x);
}
__device__ __forceinline__ float fast_softplus(float v) {
    const float e = fast_exp2(fabsf(v) * -1.4426950408889634f);  // exp(-|v|)
    const float l = fast_log2(1.0f + e) * 0.6931471805599453f;   // ln(1+e)
    return fmaxf(v, 0.0f) + l;
}
__device__ __forceinline__ short f2bf(float f) {
    __hip_bfloat16 h = __float2bfloat16(f);   // RNE
    return __builtin_bit_cast(short, h);
}

// MFMA 16x16x32 layouts (verified in rounds 2-3, guide m89/m91):
//   A: lane holds A[m = lane&15][k = (lane>>4)*8 + j]
//   B: lane holds B[k = (lane>>4)*8 + j][n = lane&15]
//   C/D: lane holds D[row = (lane>>4)*4 + reg][col = lane&15]
//
// K-permutation for GEMM1 (contraction is permutation-invariant):
//   k 0..15  -> t_feat col k   (W1 row k+2)
//   k 16     -> tanh(x0)       (W1 row 0)
//   k 17     -> tanh(x1)       (W1 row 1)
//   k 18..31 -> zero
// So the A-fragment needs NO LDS staging: lanes q<2 do two coalesced float4
// loads of t_feat; lanes q==2 compute the two tanh values; q==3 is all zero.
__global__ void __launch_bounds__(256) coupling_mfma2(
    const float* __restrict__ x, const float* __restrict__ t_feat,
    const float* __restrict__ mask, const float* __restrict__ W1,
    const float* __restrict__ b1, const float* __restrict__ W2,
    const float* __restrict__ b2, float* __restrict__ out, int n)
{
    // All LDS is WAVE-PRIVATE: no __syncthreads anywhere. Within-wave
    // write->read ordering is handled by compiler-inserted lgkmcnt waits.
    __shared__ __align__(16) char  lds_h[WAVES][16 * HSTRIDE]; // h tile, bf16
    __shared__ float lds_d[WAVES][64][11];                     // d per point (stride 11: conflict-free)

    const int wave = threadIdx.x >> 6;
    const int lane = threadIdx.x & 63;
    const int m    = lane & 15;
    const int q    = lane >> 4;
    const long nl  = n;

    // ---- weight fragments: loaded once, resident in VGPRs ----
    bf16x8 w1f[4];   // GEMM1 B-frags with the k-permutation above
#pragma unroll
    for (int a = 0; a < 4; ++a) {
        bf16x8 f;
#pragma unroll
        for (int j = 0; j < 8; ++j) {
            const int k = q * 8 + j;
            float v = 0.0f;
            if (k < 16)       v = W1[(k + 2) * 64 + 16 * a + m];
            else if (k == 16) v = W1[0 * 64 + 16 * a + m];
            else if (k == 17) v = W1[1 * 64 + 16 * a + m];
            f[j] = f2bf(v);
        }
        w1f[a] = f;
    }
    bf16x8 w2f[2];   // GEMM2 B-frags (verified round 3)
#pragma unroll
    for (int fi = 0; fi < 2; ++fi) {
        bf16x8 f;
#pragma unroll
        for (int j = 0; j < 8; ++j) {
            const int k = 32 * fi + q * 8 + j;
            const float v = (m < 10) ? W2[k * 10 + m] : 0.0f;
            f[j] = f2bf(v);
        }
        w2f[fi] = f;
    }
    float bias1[4];
#pragma unroll
    for (int a = 0; a < 4; ++a) bias1[a] = b1[16 * a + m];
    const float bias2 = (m < 10) ? b2[m] : 0.0f;
    const float m0 = mask[0], m1 = mask[1];

    char* const hb = lds_h[wave];

    for (int it = 0; it < TPW; ++it) {
        const long p0 = ((long)blockIdx.x * TPW + it) * (WAVES * 64) + wave * 64;

        // ==== 4 sub-tiles of 16 points: GEMM1 -> h -> GEMM2 -> d ====
#pragma unroll
        for (int s = 0; s < 4; ++s) {
            const long ptb  = p0 + 16 * s;
            const long prow = min(ptb + m, nl - 1);

            // ---- A-fragment, direct from global ----
            bf16x8 af;
#pragma unroll
            for (int j = 0; j < 8; ++j) af[j] = 0;
            if (q < 2) {
                const float* tr = t_feat + prow * 16 + q * 8;  // 16B-aligned
                const float4 t0 = ((const float4*)tr)[0];
                const float4 t1 = ((const float4*)tr)[1];
                af[0] = f2bf(t0.x); af[1] = f2bf(t0.y);
                af[2] = f2bf(t0.z); af[3] = f2bf(t0.w);
                af[4] = f2bf(t1.x); af[5] = f2bf(t1.y);
                af[6] = f2bf(t1.z); af[7] = f2bf(t1.w);
            } else if (q == 2) {
                const float* xr = x + prow * 3;
                af[0] = f2bf(fast_tanh(xr[0]));
                af[1] = f2bf(fast_tanh(xr[1]));
            }

            // ---- GEMM1: 4 MFMAs over hid tiles ----
            f32x4 acc[4];
#pragma unroll
            for (int a = 0; a < 4; ++a) {
                f32x4 c; c[0] = c[1] = c[2] = c[3] = bias1[a];
                acc[a] = __builtin_amdgcn_mfma_f32_16x16x32_bf16(af, w1f[a], c, 0, 0, 0);
            }

            // ---- relu + store h (bf16) to wave-private LDS ----
            // bank pattern: 2-way max (m-pairs share a dword; q vs q+2 2-way) = free
#pragma unroll
            for (int a = 0; a < 4; ++a) {
#pragma unroll
                for (int r = 0; r < 4; ++r) {
                    *(short*)(hb + (q * 4 + r) * HSTRIDE + (16 * a + m) * 2) =
                        f2bf(fmaxf(acc[a][r], 0.0f));
                }
            }

            // ---- GEMM2: read A-frags (2x ds_read_b128), 2 MFMAs ----
            const bf16x8 a20 = *(const bf16x8*)(hb + m * HSTRIDE + q * 16);
            const bf16x8 a21 = *(const bf16x8*)(hb + m * HSTRIDE + 64 + q * 16);
            f32x4 cd; cd[0] = cd[1] = cd[2] = cd[3] = bias2;
            cd = __builtin_amdgcn_mfma_f32_16x16x32_bf16(a20, w2f[0], cd, 0, 0, 0);
            cd = __builtin_amdgcn_mfma_f32_16x16x32_bf16(a21, w2f[1], cd, 0, 0, 0);

            // ---- softplus + d to LDS ----
#pragma unroll
            for (int r = 0; r < 4; ++r) {
                const float dv = fast_softplus(cd[r]) + 0.0001f;
                if (m < 10) lds_d[wave][16 * s + q * 4 + r][m] = dv;
            }
        }

        // ==== interp + store: all 64 lanes, one point each ====
        const long p = p0 + lane;
        if (p < nl) {
            const float* dd = lds_d[wave][lane];
            const float dxl2 = dd[0], dxl1 = dd[1], dxr1 = dd[2], dxr2 = dd[3];
            const float dyl2 = dd[4], dyl1 = dd[5], dyr1 = dd[6], dyr2 = dd[7];
            const float kl = dd[8] * 2.0f, kr = dd[9] * 2.0f;

            const float xL1 = -dxl1,        yL1 = -dyl1;
            const float xL2 = -dxl1 - dxl2, yL2 = -dyl1 - dyl2;
            const float xR1 = dxr1,         yR1 = dyr1;
            const float xR2 = dxr1 + dxr2,  yR2 = dyr1 + dyr2;
            const float xR3 = xR2 + BIGC,   yR3 = fmaf(kr, BIGC, yR2);
            const float xL3 = xL2 - BIGC,   yL3 = fmaf(-kl, BIGC, yL2);

            const float* xr = x + p * 3;
            const float x0v = xr[0], x1v = xr[1], x2v = xr[2];

            float qx = fminf(fmaxf(x2v, xL3 * 0.99f), xR3 * 0.99f);
            float xl = xL3, xrr = xL2, yl = yL3, yr = yL2;
            if (qx >= xL2) { xl = xL2; xrr = xL1; yl = yL2; yr = yL1; }
            if (qx >= xL1) { xl = xL1; xrr = xR1; yl = yL1; yr = yR1; }
            if (qx >= xR1) { xl = xR1; xrr = xR2; yl = yR1; yr = yR2; }
            if (qx >= xR2) { xl = xR2; xrr = xR3; yl = yR2; yr = yR3; }
            const float slope = (yr - yl) * fast_rcp(xrr - xl);
            const float res = fmaf(slope, qx - xl, yl);

            out[p * 3 + 0] = x0v * m0;
            out[p * 3 + 1] = x1v * m1;
            out[p * 3 + 2] = res;
        }
    }
}

extern "C" void kernel_launch(void* const* d_in, const int* in_sizes, int n_in,
                              void* d_out, int out_size, void* d_ws, size_t ws_size,
                              hipStream_t stream) {
    const float* x      = (const float*)d_in[0];
    const float* t_feat = (const float*)d_in[1];
    const float* mask   = (const float*)d_in[2];
    const float* W1     = (const float*)d_in[3];
    const float* b1     = (const float*)d_in[4];
    const float* W2     = (const float*)d_in[5];
    const float* b2     = (const float*)d_in[6];
    float* out = (float*)d_out;

    const int n = in_sizes[0] / 3;                     // 2097152 points
    const int pts_per_block = TPW * WAVES * 64;        // 1024
    const int grid = (n + pts_per_block - 1) / pts_per_block;  // 2048
    coupling_mfma2<<<grid, 256, 0, stream>>>(x, t_feat, mask, W1, b1, W2, b2, out, n);
}

// Round 5
// 263.958 us; speedup vs baseline: 1.3205x; 1.0098x over previous
//
#include <hip/hip_runtime.h>
#include <hip/hip_bf16.h>

typedef __attribute__((ext_vector_type(8))) short bf16x8;  // 8 bf16 = 4 VGPRs
typedef __attribute__((ext_vector_type(4))) float f32x4;   // MFMA C/D
typedef __attribute__((ext_vector_type(4))) int   i32x4;

#define BIGC 10000.0f
#define TPW 4          // macro-iterations (64 points per wave each)
#define WAVES 4

__device__ __forceinline__ float fast_exp2(float x) { return __builtin_amdgcn_exp2f(x); }
__device__ __forceinline__ float fast_log2(float x) { return __builtin_amdgcn_logf(x); }
__device__ __forceinline__ float fast_rcp(float x)  { return __builtin_amdgcn_rcpf(x); }

__device__ __forceinline__ float fast_tanh(float x) {
    const float ax = fabsf(x);
    const float e  = fast_exp2(ax * 2.8853900817779268f);   // e^(2|x|)
    const float r  = 1.0f - 2.0f * fast_rcp(e + 1.0f);
    return copysignf(r, x);
}
__device__ __forceinline__ float fast_softplus(float v) {
    const float e = fast_exp2(fabsf(v) * -1.4426950408889634f);  // exp(-|v|)
    const float l = fast_log2(1.0f + e) * 0.6931471805599453f;   // ln(1+e)
    return fmaxf(v, 0.0f) + l;
}
// Pack two f32 -> two bf16 (round-half-up) in ONE dword: 2 v_add + 1 v_perm.
__device__ __forceinline__ unsigned pack2bf(float hi, float lo) {
    const unsigned uh = __builtin_bit_cast(unsigned, hi) + 0x8000u;
    const unsigned ul = __builtin_bit_cast(unsigned, lo) + 0x8000u;
    return __builtin_amdgcn_perm(uh, ul, 0x07060302u);  // [hi.top16 | lo.top16]
}

// MFMA 16x16x32 layouts (verified rounds 2-4):
//   A: lane holds A[m=lane&15][k=(lane>>4)*8+j]
//   B: lane holds B[k=(lane>>4)*8+j][n=lane&15]
//   C/D: lane holds D[row=(lane>>4)*4+reg][col=lane&15]
//
// GEMM1 TRANSPOSED: h^T(64x16) = W1'^T(64x19) @ z^T(19x16), 4 M-tiles (a).
//   z k-slots: k<16 -> t_feat[k]; k=16 -> tanh(x0); k=17 -> tanh(x1);
//              k=18 -> 1.0 (bias row, A value = b1); k>18 -> 0.
//   D: lane (q,m) reg r of tile a = h[point=m][hid=16a+4q+r].
// GEMM2 NORMAL: d(16x10) = h(16x64) @ W2sig(64x10), K-permutation
//   sigma(k): bits [fi|q1q0|j2|j1j0] -> hid [fi|j2|q1q0|j1j0], folded into W2
//   row order. Then A-frag(fi)[j] = relu(acc[2fi+(j>>2)][j&3])  -- SAME LANE,
//   zero cross-lane movement, no LDS for h.
__global__ void __launch_bounds__(256) coupling_mfma3(
    const float* __restrict__ x, const float* __restrict__ t_feat,
    const float* __restrict__ mask, const float* __restrict__ W1,
    const float* __restrict__ b1, const float* __restrict__ W2,
    const float* __restrict__ b2, float* __restrict__ out, int n)
{
    // Only d needs LDS (feat index must move across lanes for interp).
    // Wave-private; stride 11 dwords (gcd(11,32)=1 -> conflict-free).
    __shared__ float lds_d[WAVES][64][11];

    const int wave = threadIdx.x >> 6;
    const int lane = threadIdx.x & 63;
    const int m    = lane & 15;
    const int q    = lane >> 4;
    const long nl  = n;

    // ---- constant fragments (built once, resident in VGPRs) ----
    bf16x8 w1f[4];   // GEMM1 A-frags: lane (q,m) elem j = W1row(sigma_z(8q+j))[16a+m]
#pragma unroll
    for (int a = 0; a < 4; ++a) {
        float wv[8];
#pragma unroll
        for (int j = 0; j < 8; ++j) {
            const int k = q * 8 + j;
            const int col = 16 * a + m;
            float v = 0.0f;
            if (k < 16)       v = W1[(k + 2) * 64 + col];
            else if (k == 16) v = W1[0 * 64 + col];
            else if (k == 17) v = W1[1 * 64 + col];
            else if (k == 18) v = b1[col];          // bias folded in
            wv[j] = v;
        }
        i32x4 f = { (int)pack2bf(wv[1], wv[0]), (int)pack2bf(wv[3], wv[2]),
                    (int)pack2bf(wv[5], wv[4]), (int)pack2bf(wv[7], wv[6]) };
        w1f[a] = __builtin_bit_cast(bf16x8, f);
    }
    bf16x8 w2f[2];   // GEMM2 B-frags with sigma row-permutation
#pragma unroll
    for (int fi = 0; fi < 2; ++fi) {
        float wv[8];
#pragma unroll
        for (int j = 0; j < 8; ++j) {
            const int hid = 32 * fi + 16 * (j >> 2) + 4 * q + (j & 3);
            wv[j] = (m < 10) ? W2[hid * 10 + m] : 0.0f;
        }
        i32x4 f = { (int)pack2bf(wv[1], wv[0]), (int)pack2bf(wv[3], wv[2]),
                    (int)pack2bf(wv[5], wv[4]), (int)pack2bf(wv[7], wv[6]) };
        w2f[fi] = __builtin_bit_cast(bf16x8, f);
    }
    const float bias2 = (m < 10) ? b2[m] : 0.0f;
    const float m0 = mask[0], m1 = mask[1];

    for (int it = 0; it < TPW; ++it) {
        const long p0 = ((long)blockIdx.x * TPW + it) * (WAVES * 64) + wave * 64;

        // ==== 4 sub-tiles of 16 points ====
#pragma unroll
        for (int s = 0; s < 4; ++s) {
            const long prow = min(p0 + 16 * s + m, nl - 1);

            // ---- B-frag of z^T, direct from global (no staging) ----
            i32x4 zw = { 0, 0, 0, 0 };
            if (q < 2) {
                const float* tr = t_feat + prow * 16 + q * 8;   // 16B-aligned
                const float4 t0 = ((const float4*)tr)[0];
                const float4 t1 = ((const float4*)tr)[1];
                zw[0] = (int)pack2bf(t0.y, t0.x);
                zw[1] = (int)pack2bf(t0.w, t0.z);
                zw[2] = (int)pack2bf(t1.y, t1.x);
                zw[3] = (int)pack2bf(t1.w, t1.z);
            } else if (q == 2) {
                const float* xr = x + prow * 3;
                zw[0] = (int)pack2bf(fast_tanh(xr[1]), fast_tanh(xr[0]));
                zw[1] = 0x3F80;                    // k=18: bf16(1.0) bias slot
            }
            const bf16x8 zf = __builtin_bit_cast(bf16x8, zw);

            // ---- GEMM1 (transposed): 4 independent MFMAs, bias folded ----
            f32x4 acc[4];
#pragma unroll
            for (int a = 0; a < 4; ++a) {
                f32x4 c = { 0.0f, 0.0f, 0.0f, 0.0f };
                acc[a] = __builtin_amdgcn_mfma_f32_16x16x32_bf16(w1f[a], zf, c, 0, 0, 0);
            }

            // ---- relu + IN-LANE repack to GEMM2 A-frags (no LDS!) ----
            float rl[16];
#pragma unroll
            for (int a = 0; a < 4; ++a)
#pragma unroll
                for (int r = 0; r < 4; ++r)
                    rl[4 * a + r] = fmaxf(acc[a][r], 0.0f);
            i32x4 a20 = { (int)pack2bf(rl[1],  rl[0]),  (int)pack2bf(rl[3],  rl[2]),
                          (int)pack2bf(rl[5],  rl[4]),  (int)pack2bf(rl[7],  rl[6]) };
            i32x4 a21 = { (int)pack2bf(rl[9],  rl[8]),  (int)pack2bf(rl[11], rl[10]),
                          (int)pack2bf(rl[13], rl[12]), (int)pack2bf(rl[15], rl[14]) };

            // ---- GEMM2: two INDEPENDENT MFMAs, summed after ----
            f32x4 cb = { bias2, bias2, bias2, bias2 };
            f32x4 cz = { 0.0f, 0.0f, 0.0f, 0.0f };
            f32x4 cd0 = __builtin_amdgcn_mfma_f32_16x16x32_bf16(
                            __builtin_bit_cast(bf16x8, a20), w2f[0], cb, 0, 0, 0);
            f32x4 cd1 = __builtin_amdgcn_mfma_f32_16x16x32_bf16(
                            __builtin_bit_cast(bf16x8, a21), w2f[1], cz, 0, 0, 0);

            // ---- softplus + d to LDS (2-way max bank aliasing = free) ----
#pragma unroll
            for (int r = 0; r < 4; ++r) {
                const float dv = fast_softplus(cd0[r] + cd1[r]) + 0.0001f;
                if (m < 10) lds_d[wave][16 * s + 4 * q + r][m] = dv;
            }
        }

        // ==== interp + store: all 64 lanes, one point each ====
        const long p = p0 + lane;
        if (p < nl) {
            const float* dd = lds_d[wave][lane];
            const float dxl2 = dd[0], dxl1 = dd[1], dxr1 = dd[2], dxr2 = dd[3];
            const float dyl2 = dd[4], dyl1 = dd[5], dyr1 = dd[6], dyr2 = dd[7];
            const float kl = dd[8] * 2.0f, kr = dd[9] * 2.0f;

            const float xL1 = -dxl1,        yL1 = -dyl1;
            const float xL2 = -dxl1 - dxl2, yL2 = -dyl1 - dyl2;
            const float xR1 = dxr1,         yR1 = dyr1;
            const float xR2 = dxr1 + dxr2,  yR2 = dyr1 + dyr2;
            const float xR3 = xR2 + BIGC,   yR3 = fmaf(kr, BIGC, yR2);
            const float xL3 = xL2 - BIGC,   yL3 = fmaf(-kl, BIGC, yL2);

            const float* xr = x + p * 3;
            const float x0v = xr[0], x1v = xr[1], x2v = xr[2];

            float qx = fminf(fmaxf(x2v, xL3 * 0.99f), xR3 * 0.99f);
            float xl = xL3, xrr = xL2, yl = yL3, yr = yL2;
            if (qx >= xL2) { xl = xL2; xrr = xL1; yl = yL2; yr = yL1; }
            if (qx >= xL1) { xl = xL1; xrr = xR1; yl = yL1; yr = yR1; }
            if (qx >= xR1) { xl = xR1; xrr = xR2; yl = yR1; yr = yR2; }
            if (qx >= xR2) { xl = xR2; xrr = xR3; yl = yR2; yr = yR3; }
            const float slope = (yr - yl) * fast_rcp(xrr - xl);
            const float res = fmaf(slope, qx - xl, yl);

            out[p * 3 + 0] = x0v * m0;
            out[p * 3 + 1] = x1v * m1;
            out[p * 3 + 2] = res;
        }
    }
}

extern "C" void kernel_launch(void* const* d_in, const int* in_sizes, int n_in,
                              void* d_out, int out_size, void* d_ws, size_t ws_size,
                              hipStream_t stream) {
    const float* x      = (const float*)d_in[0];
    const float* t_feat = (const float*)d_in[1];
    const float* mask   = (const float*)d_in[2];
    const float* W1     = (const float*)d_in[3];
    const float* b1     = (const float*)d_in[4];
    const float* W2     = (const float*)d_in[5];
    const float* b2     = (const float*)d_in[6];
    float* out = (float*)d_out;

    const int n = in_sizes[0] / 3;                       // 2097152 points
    const int pts_per_block = TPW * WAVES * 64;          // 1024
    const int grid = (n + pts_per_block - 1) / pts_per_block;   // 2048
    coupling_mfma3<<<grid, 256, 0, stream>>>(x, t_feat, mask, W1, b1, W2, b2, out, n);
}